// Round 6
// baseline (212.384 us; speedup 1.0000x reference)
//
#include <hip/hip_runtime.h>
#include <float.h>
#include <math.h>

#define BB 32
#define SS 1024
#define DD 512
#define NCH 32          // chunks per batch (32 rows each)
#define CROWS 32
#define RW 8            // rows per wave

typedef float f32x4 __attribute__((ext_vector_type(4)));

__device__ __forceinline__ float wave_reduce_add(float v) {
    #pragma unroll
    for (int m = 32; m >= 1; m >>= 1) v += __shfl_xor(v, m, 64);
    return v;
}

// ---------------- K1: copy + xsum partials + LOCAL online-softmax chunk partials ----
// grid (BB, NCH), 256 threads = 4 waves x 8 rows.
__global__ __launch_bounds__(256) void k_pass1(
    const float* __restrict__ x, const float* __restrict__ w_score,
    const int* __restrict__ x_len, float* __restrict__ out_x,
    float* __restrict__ xsum_part, float* __restrict__ lP,
    float* __restrict__ lm, float* __restrict__ lS)
{
    __shared__ float red_xsum[4][DD];
    __shared__ float red_ctx[4][DD];
    __shared__ float m_s[4], S_s[4];
    int b = blockIdx.x, sc = blockIdx.y;
    int wave = threadIdx.x >> 6, lane = threadIdx.x & 63, tid = threadIdx.x;
    int len = x_len[b];
    int s0 = sc * CROWS + wave * RW;
    size_t base = ((size_t)b * SS + s0) * DD;

    const f32x4* wr = (const f32x4*)w_score;
    f32x4 w0 = wr[lane], w1 = wr[lane + 64];

    f32x4 a[RW][2];
    #pragma unroll
    for (int r = 0; r < RW; ++r) {
        const f32x4* xr = (const f32x4*)(x + base + (size_t)r * DD);
        a[r][0] = xr[lane];
        a[r][1] = xr[lane + 64];
    }
    #pragma unroll
    for (int r = 0; r < RW; ++r) {
        f32x4* orow = (f32x4*)(out_x + base + (size_t)r * DD);
        __builtin_nontemporal_store(a[r][0], &orow[lane]);
        __builtin_nontemporal_store(a[r][1], &orow[lane + 64]);
    }
    float p[RW];
    f32x4 acc0 = {0,0,0,0}, acc1 = {0,0,0,0};
    #pragma unroll
    for (int r = 0; r < RW; ++r) {
        f32x4 t0 = a[r][0] * w0 + a[r][1] * w1;
        p[r] = t0.x + t0.y + t0.z + t0.w;
        acc0 += a[r][0];
        acc1 += a[r][1];
    }
    #pragma unroll
    for (int r = 0; r < RW; ++r) p[r] = wave_reduce_add(p[r]);
    float mw = -FLT_MAX;
    #pragma unroll
    for (int r = 0; r < RW; ++r) if (s0 + r < len) mw = fmaxf(mw, p[r]);
    float Sw = 0.f;
    f32x4 c0 = {0,0,0,0}, c1 = {0,0,0,0};
    #pragma unroll
    for (int r = 0; r < RW; ++r) {
        float wgt = (s0 + r < len) ? __expf(p[r] - mw) : 0.f;
        Sw += wgt;
        c0 += wgt * a[r][0];
        c1 += wgt * a[r][1];
    }
    f32x4* rx = (f32x4*)red_xsum[wave];
    f32x4* rc = (f32x4*)red_ctx[wave];
    rx[lane] = acc0; rx[lane + 64] = acc1;
    rc[lane] = c0;   rc[lane + 64] = c1;
    if (lane == 0) { m_s[wave] = mw; S_s[wave] = Sw; }
    __syncthreads();
    float mc = fmaxf(fmaxf(m_s[0], m_s[1]), fmaxf(m_s[2], m_s[3]));
    float e0 = __expf(m_s[0] - mc), e1 = __expf(m_s[1] - mc);
    float e2 = __expf(m_s[2] - mc), e3 = __expf(m_s[3] - mc);
    #pragma unroll
    for (int i = 0; i < 2; ++i) {
        int d = tid + i * 256;
        size_t off = ((size_t)b * NCH + sc) * DD + d;
        xsum_part[off] = red_xsum[0][d] + red_xsum[1][d] + red_xsum[2][d] + red_xsum[3][d];
        lP[off] = red_ctx[0][d]*e0 + red_ctx[1][d]*e1 + red_ctx[2][d]*e2 + red_ctx[3][d]*e3;
    }
    if (tid == 0) {
        lm[b * NCH + sc] = mc;
        lS[b * NCH + sc] = S_s[0]*e0 + S_s[1]*e1 + S_s[2]*e2 + S_s[3]*e3;
    }
}

// ---------------- K2: fused xsum-reduce + ks (full) + v (final) ----------------
// grid (2 d-halves, BB), 256 threads. v[b][d] = sum_e Wq[d][e] * ks[b][e],
// ks[b][e] = sum_d xsum[b][d] * Wk[d][e] + SS*bk[e].
__global__ __launch_bounds__(256) void k_v2(
    const float* __restrict__ xsum_part, const float* __restrict__ Wk,
    const float* __restrict__ Wq, const float* __restrict__ bk,
    float* __restrict__ v)
{
    __shared__ float xs[DD];
    __shared__ float ks[DD];
    __shared__ float tile[256][65];
    int dh = blockIdx.x, b = blockIdx.y, tid = threadIdx.x;
    // xsum reduce over 32 chunks
    #pragma unroll
    for (int i = 0; i < 2; ++i) {
        int d = tid + i * 256;
        float s = 0.f;
        #pragma unroll 8
        for (int sc = 0; sc < NCH; ++sc)
            s += xsum_part[((size_t)b * NCH + sc) * DD + d];
        xs[d] = s;
    }
    __syncthreads();
    // full ks: threads own e = tid, tid+256
    float k0 = (float)SS * bk[tid], k1 = (float)SS * bk[tid + 256];
    #pragma unroll 8
    for (int d = 0; d < DD; ++d) {
        float xv = xs[d];
        k0 += xv * Wk[(size_t)d * DD + tid];
        k1 += xv * Wk[(size_t)d * DD + tid + 256];
    }
    ks[tid] = k0; ks[tid + 256] = k1;
    __syncthreads();
    // v for my 256-d half: LDS-tiled Wq
    int d0 = dh * 256;
    float acc = 0.f;
    for (int ec = 0; ec < 8; ++ec) {
        #pragma unroll
        for (int it = 0; it < 16; ++it) {
            int idx = tid + it * 256;
            int rowd = idx >> 4, col4 = idx & 15;
            f32x4 wv = *(const f32x4*)(Wq + (size_t)(d0 + rowd) * DD + ec * 64 + col4 * 4);
            float* dst = &tile[rowd][col4 * 4];
            dst[0] = wv.x; dst[1] = wv.y; dst[2] = wv.z; dst[3] = wv.w;
        }
        __syncthreads();
        #pragma unroll 8
        for (int el = 0; el < 64; ++el)
            acc += tile[tid][el] * ks[ec * 64 + el];
        __syncthreads();
    }
    v[(size_t)b * DD + d0 + tid] = acc;
}

// ---------------- K3: g-scores + GLOBAL online-softmax partials + last-block merge ----
__global__ __launch_bounds__(256) void k_pass2(
    const float* __restrict__ x, const float* __restrict__ v,
    const int* __restrict__ x_len,
    const float* __restrict__ lP, const float* __restrict__ lm, const float* __restrict__ lS,
    float* __restrict__ gP, float* __restrict__ gm, float* __restrict__ gS,
    int* __restrict__ cnt, const int* __restrict__ slot_idx,
    const float* __restrict__ beta_raw, float* __restrict__ out_c)
{
    __shared__ float v_lds[DD];
    __shared__ float red_ctx[4][DD];
    __shared__ float m_s[4], S_s[4];
    __shared__ int lastflag;
    int b = blockIdx.x, sc = blockIdx.y;
    int wave = threadIdx.x >> 6, lane = threadIdx.x & 63, tid = threadIdx.x;
    int len = x_len[b];
    int s0 = sc * CROWS + wave * RW;
    size_t base = ((size_t)b * SS + s0) * DD;

    v_lds[tid] = v[(size_t)b * DD + tid];
    v_lds[tid + 256] = v[(size_t)b * DD + tid + 256];
    __syncthreads();
    const f32x4* vr = (const f32x4*)v_lds;
    f32x4 v0 = vr[lane], v1 = vr[lane + 64];

    f32x4 a[RW][2];
    #pragma unroll
    for (int r = 0; r < RW; ++r) {
        const f32x4* xr = (const f32x4*)(x + base + (size_t)r * DD);
        a[r][0] = xr[lane];
        a[r][1] = xr[lane + 64];
    }
    float p[RW];
    #pragma unroll
    for (int r = 0; r < RW; ++r) {
        f32x4 t0 = a[r][0] * v0 + a[r][1] * v1;
        p[r] = t0.x + t0.y + t0.z + t0.w;
    }
    #pragma unroll
    for (int r = 0; r < RW; ++r)
        p[r] = wave_reduce_add(p[r]) * 0.04419417382415922f;
    float mw = -FLT_MAX;
    #pragma unroll
    for (int r = 0; r < RW; ++r) if (s0 + r < len) mw = fmaxf(mw, p[r]);
    float Sw = 0.f;
    f32x4 c0 = {0,0,0,0}, c1 = {0,0,0,0};
    #pragma unroll
    for (int r = 0; r < RW; ++r) {
        float wgt = (s0 + r < len) ? __expf(p[r] - mw) : 0.f;
        Sw += wgt;
        c0 += wgt * a[r][0];
        c1 += wgt * a[r][1];
    }
    f32x4* rc = (f32x4*)red_ctx[wave];
    rc[lane] = c0; rc[lane + 64] = c1;
    if (lane == 0) { m_s[wave] = mw; S_s[wave] = Sw; }
    __syncthreads();
    float mc = fmaxf(fmaxf(m_s[0], m_s[1]), fmaxf(m_s[2], m_s[3]));
    float e0 = __expf(m_s[0] - mc), e1 = __expf(m_s[1] - mc);
    float e2 = __expf(m_s[2] - mc), e3 = __expf(m_s[3] - mc);
    #pragma unroll
    for (int i = 0; i < 2; ++i) {
        int d = tid + i * 256;
        size_t off = ((size_t)b * NCH + sc) * DD + d;
        gP[off] = red_ctx[0][d]*e0 + red_ctx[1][d]*e1 + red_ctx[2][d]*e2 + red_ctx[3][d]*e3;
    }
    if (tid == 0) {
        gm[b * NCH + sc] = mc;
        gS[b * NCH + sc] = S_s[0]*e0 + S_s[1]*e1 + S_s[2]*e2 + S_s[3]*e3;
    }
    // ---- last block per batch performs the merge (threadfence reduction) ----
    __threadfence();
    if (tid == 0) {
        int old = atomicAdd(&cnt[b], 1);
        lastflag = (old == NCH - 1);
    }
    __syncthreads();
    if (!lastflag) return;
    __threadfence();

    float Ml = -FLT_MAX, Mg = -FLT_MAX;
    #pragma unroll 8
    for (int c = 0; c < NCH; ++c) {
        Ml = fmaxf(Ml, lm[b * NCH + c]);
        Mg = fmaxf(Mg, gm[b * NCH + c]);
    }
    float Sl = 0.f, Sg = 0.f;
    float Pl0 = 0.f, Pl1 = 0.f, Pg0 = 0.f, Pg1 = 0.f;
    #pragma unroll 4
    for (int c = 0; c < NCH; ++c) {
        float wl = __expf(lm[b * NCH + c] - Ml);
        float wg = __expf(gm[b * NCH + c] - Mg);
        Sl += lS[b * NCH + c] * wl;
        Sg += gS[b * NCH + c] * wg;
        size_t off = ((size_t)b * NCH + c) * DD + tid;
        Pl0 += lP[off] * wl;
        Pl1 += lP[off + 256] * wl;
        Pg0 += gP[off] * wg;
        Pg1 += gP[off + 256] * wg;
    }
    float br = beta_raw[slot_idx[0]];
    float beta = 1.f / (1.f + __expf(-br));
    float rb = 1.f - beta;
    out_c[(size_t)b * DD + tid]       = beta * Pl0 / Sl + rb * Pg0 / Sg;
    out_c[(size_t)b * DD + tid + 256] = beta * Pl1 / Sl + rb * Pg1 / Sg;
}

extern "C" void kernel_launch(void* const* d_in, const int* in_sizes, int n_in,
                              void* d_out, int out_size, void* d_ws, size_t ws_size,
                              hipStream_t stream) {
    const float* x        = (const float*)d_in[0];
    const int*   x_len    = (const int*)d_in[1];
    const int*   slot_idx = (const int*)d_in[2];
    const float* w_score  = (const float*)d_in[3];
    // d_in[4] = b_score (softmax shift-invariant, unused)
    const float* Wq       = (const float*)d_in[5];
    // d_in[6] = bq (only affects shift-invariant t, unused)
    const float* Wk       = (const float*)d_in[7];
    const float* bk       = (const float*)d_in[8];
    const float* beta_raw = (const float*)d_in[9];

    float* out   = (float*)d_out;
    float* out_x = out;                           // [B,S,D]
    float* out_c = out + (size_t)BB * SS * DD;    // [B,D]

    float* ws = (float*)d_ws;
    float* xsum_part = ws;                        // 32*32*512 = 524288
    float* lP        = ws + 524288;               // 524288
    float* gP        = ws + 1048576;              // 524288
    float* v         = ws + 1572864;              // 16384
    float* lm        = ws + 1589248;              // 1024
    float* lS        = ws + 1590272;              // 1024
    float* gm        = ws + 1591296;              // 1024
    float* gS        = ws + 1592320;              // 1024
    int*   cnt       = (int*)(ws + 1593344);      // 32 ints

    hipMemsetAsync(cnt, 0, BB * sizeof(int), stream);
    k_pass1<<<dim3(BB, NCH), 256, 0, stream>>>(x, w_score, x_len, out_x, xsum_part, lP, lm, lS);
    k_v2<<<dim3(2, BB), 256, 0, stream>>>(xsum_part, Wk, Wq, bk, v);
    k_pass2<<<dim3(BB, NCH), 256, 0, stream>>>(x, v, x_len, lP, lm, lS, gP, gm, gS,
                                               cnt, slot_idx, beta_raw, out_c);
}

// Round 7
// 83.625 us; speedup vs baseline: 2.5397x; 2.5397x over previous
//
#include <hip/hip_runtime.h>
#include <float.h>
#include <math.h>

#define BB 32
#define SS 1024
#define DD 512
#define NCH 32          // chunks per batch (32 rows each)
#define CROWS 32
#define RW 8            // rows per wave

typedef float f32x4 __attribute__((ext_vector_type(4)));

__device__ __forceinline__ float wave_reduce_add(float v) {
    #pragma unroll
    for (int m = 32; m >= 1; m >>= 1) v += __shfl_xor(v, m, 64);
    return v;
}

// ---------------- K1: copy + xsum partials + LOCAL online-softmax chunk partials ----
// grid (BB, NCH), 256 threads = 4 waves x 8 rows.
__global__ __launch_bounds__(256) void k_pass1(
    const float* __restrict__ x, const float* __restrict__ w_score,
    const int* __restrict__ x_len, float* __restrict__ out_x,
    float* __restrict__ xsum_part, float* __restrict__ lP,
    float* __restrict__ lm, float* __restrict__ lS)
{
    __shared__ float red_xsum[4][DD];
    __shared__ float red_ctx[4][DD];
    __shared__ float m_s[4], S_s[4];
    int b = blockIdx.x, sc = blockIdx.y;
    int wave = threadIdx.x >> 6, lane = threadIdx.x & 63, tid = threadIdx.x;
    int len = x_len[b];
    int s0 = sc * CROWS + wave * RW;
    size_t base = ((size_t)b * SS + s0) * DD;

    const f32x4* wr = (const f32x4*)w_score;
    f32x4 w0 = wr[lane], w1 = wr[lane + 64];

    f32x4 a[RW][2];
    #pragma unroll
    for (int r = 0; r < RW; ++r) {
        const f32x4* xr = (const f32x4*)(x + base + (size_t)r * DD);
        a[r][0] = xr[lane];
        a[r][1] = xr[lane + 64];
    }
    #pragma unroll
    for (int r = 0; r < RW; ++r) {
        f32x4* orow = (f32x4*)(out_x + base + (size_t)r * DD);
        __builtin_nontemporal_store(a[r][0], &orow[lane]);
        __builtin_nontemporal_store(a[r][1], &orow[lane + 64]);
    }
    float p[RW];
    f32x4 acc0 = {0,0,0,0}, acc1 = {0,0,0,0};
    #pragma unroll
    for (int r = 0; r < RW; ++r) {
        f32x4 t0 = a[r][0] * w0 + a[r][1] * w1;
        p[r] = t0.x + t0.y + t0.z + t0.w;
        acc0 += a[r][0];
        acc1 += a[r][1];
    }
    #pragma unroll
    for (int r = 0; r < RW; ++r) p[r] = wave_reduce_add(p[r]);
    float mw = -FLT_MAX;
    #pragma unroll
    for (int r = 0; r < RW; ++r) if (s0 + r < len) mw = fmaxf(mw, p[r]);
    float Sw = 0.f;
    f32x4 c0 = {0,0,0,0}, c1 = {0,0,0,0};
    #pragma unroll
    for (int r = 0; r < RW; ++r) {
        float wgt = (s0 + r < len) ? __expf(p[r] - mw) : 0.f;
        Sw += wgt;
        c0 += wgt * a[r][0];
        c1 += wgt * a[r][1];
    }
    f32x4* rx = (f32x4*)red_xsum[wave];
    f32x4* rc = (f32x4*)red_ctx[wave];
    rx[lane] = acc0; rx[lane + 64] = acc1;
    rc[lane] = c0;   rc[lane + 64] = c1;
    if (lane == 0) { m_s[wave] = mw; S_s[wave] = Sw; }
    __syncthreads();
    float mc = fmaxf(fmaxf(m_s[0], m_s[1]), fmaxf(m_s[2], m_s[3]));
    float e0 = __expf(m_s[0] - mc), e1 = __expf(m_s[1] - mc);
    float e2 = __expf(m_s[2] - mc), e3 = __expf(m_s[3] - mc);
    #pragma unroll
    for (int i = 0; i < 2; ++i) {
        int d = tid + i * 256;
        size_t off = ((size_t)b * NCH + sc) * DD + d;
        xsum_part[off] = red_xsum[0][d] + red_xsum[1][d] + red_xsum[2][d] + red_xsum[3][d];
        lP[off] = red_ctx[0][d]*e0 + red_ctx[1][d]*e1 + red_ctx[2][d]*e2 + red_ctx[3][d]*e3;
    }
    if (tid == 0) {
        lm[b * NCH + sc] = mc;
        lS[b * NCH + sc] = S_s[0]*e0 + S_s[1]*e1 + S_s[2]*e2 + S_s[3]*e3;
    }
}

// ---------------- K2: fused xsum-reduce + ks (full) + v (final) ----------------
// grid (2 d-halves, BB), 256 threads.
__global__ __launch_bounds__(256) void k_v2(
    const float* __restrict__ xsum_part, const float* __restrict__ Wk,
    const float* __restrict__ Wq, const float* __restrict__ bk,
    float* __restrict__ v)
{
    __shared__ float xs[DD];
    __shared__ float ks[DD];
    __shared__ float tile[256][65];
    int dh = blockIdx.x, b = blockIdx.y, tid = threadIdx.x;
    #pragma unroll
    for (int i = 0; i < 2; ++i) {
        int d = tid + i * 256;
        float s = 0.f;
        #pragma unroll 8
        for (int sc = 0; sc < NCH; ++sc)
            s += xsum_part[((size_t)b * NCH + sc) * DD + d];
        xs[d] = s;
    }
    __syncthreads();
    float k0 = (float)SS * bk[tid], k1 = (float)SS * bk[tid + 256];
    #pragma unroll 8
    for (int d = 0; d < DD; ++d) {
        float xv = xs[d];
        k0 += xv * Wk[(size_t)d * DD + tid];
        k1 += xv * Wk[(size_t)d * DD + tid + 256];
    }
    ks[tid] = k0; ks[tid + 256] = k1;
    __syncthreads();
    int d0 = dh * 256;
    float acc = 0.f;
    for (int ec = 0; ec < 8; ++ec) {
        #pragma unroll
        for (int it = 0; it < 16; ++it) {
            int idx = tid + it * 256;
            int rowd = idx >> 4, col4 = idx & 15;
            f32x4 wv = *(const f32x4*)(Wq + (size_t)(d0 + rowd) * DD + ec * 64 + col4 * 4);
            float* dst = &tile[rowd][col4 * 4];
            dst[0] = wv.x; dst[1] = wv.y; dst[2] = wv.z; dst[3] = wv.w;
        }
        __syncthreads();
        #pragma unroll 8
        for (int el = 0; el < 64; ++el)
            acc += tile[tid][el] * ks[ec * 64 + el];
        __syncthreads();
    }
    v[(size_t)b * DD + d0 + tid] = acc;
}

// ---------------- K3: g-scores + GLOBAL online-softmax chunk partials ----------------
__global__ __launch_bounds__(256) void k_pass2(
    const float* __restrict__ x, const float* __restrict__ v,
    const int* __restrict__ x_len,
    float* __restrict__ gP, float* __restrict__ gm, float* __restrict__ gS)
{
    __shared__ float v_lds[DD];
    __shared__ float red_ctx[4][DD];
    __shared__ float m_s[4], S_s[4];
    int b = blockIdx.x, sc = blockIdx.y;
    int wave = threadIdx.x >> 6, lane = threadIdx.x & 63, tid = threadIdx.x;
    int len = x_len[b];
    int s0 = sc * CROWS + wave * RW;
    size_t base = ((size_t)b * SS + s0) * DD;

    v_lds[tid] = v[(size_t)b * DD + tid];
    v_lds[tid + 256] = v[(size_t)b * DD + tid + 256];
    __syncthreads();
    const f32x4* vr = (const f32x4*)v_lds;
    f32x4 v0 = vr[lane], v1 = vr[lane + 64];

    f32x4 a[RW][2];
    #pragma unroll
    for (int r = 0; r < RW; ++r) {
        const f32x4* xr = (const f32x4*)(x + base + (size_t)r * DD);
        a[r][0] = xr[lane];
        a[r][1] = xr[lane + 64];
    }
    float p[RW];
    #pragma unroll
    for (int r = 0; r < RW; ++r) {
        f32x4 t0 = a[r][0] * v0 + a[r][1] * v1;
        p[r] = t0.x + t0.y + t0.z + t0.w;
    }
    #pragma unroll
    for (int r = 0; r < RW; ++r)
        p[r] = wave_reduce_add(p[r]) * 0.04419417382415922f;
    float mw = -FLT_MAX;
    #pragma unroll
    for (int r = 0; r < RW; ++r) if (s0 + r < len) mw = fmaxf(mw, p[r]);
    float Sw = 0.f;
    f32x4 c0 = {0,0,0,0}, c1 = {0,0,0,0};
    #pragma unroll
    for (int r = 0; r < RW; ++r) {
        float wgt = (s0 + r < len) ? __expf(p[r] - mw) : 0.f;
        Sw += wgt;
        c0 += wgt * a[r][0];
        c1 += wgt * a[r][1];
    }
    f32x4* rc = (f32x4*)red_ctx[wave];
    rc[lane] = c0; rc[lane + 64] = c1;
    if (lane == 0) { m_s[wave] = mw; S_s[wave] = Sw; }
    __syncthreads();
    float mc = fmaxf(fmaxf(m_s[0], m_s[1]), fmaxf(m_s[2], m_s[3]));
    float e0 = __expf(m_s[0] - mc), e1 = __expf(m_s[1] - mc);
    float e2 = __expf(m_s[2] - mc), e3 = __expf(m_s[3] - mc);
    #pragma unroll
    for (int i = 0; i < 2; ++i) {
        int d = tid + i * 256;
        size_t off = ((size_t)b * NCH + sc) * DD + d;
        gP[off] = red_ctx[0][d]*e0 + red_ctx[1][d]*e1 + red_ctx[2][d]*e2 + red_ctx[3][d]*e3;
    }
    if (tid == 0) {
        gm[b * NCH + sc] = mc;
        gS[b * NCH + sc] = S_s[0]*e0 + S_s[1]*e1 + S_s[2]*e2 + S_s[3]*e3;
    }
}

// ---------------- K4: merge chunk partials, beta-combine ----------------
__global__ __launch_bounds__(512) void k_combine(
    const float* __restrict__ lP, const float* __restrict__ lm, const float* __restrict__ lS,
    const float* __restrict__ gP, const float* __restrict__ gm, const float* __restrict__ gS,
    const int* __restrict__ slot_idx, const float* __restrict__ beta_raw,
    float* __restrict__ out_c)
{
    int b = blockIdx.x, d = threadIdx.x;
    float Ml = -FLT_MAX, Mg = -FLT_MAX;
    #pragma unroll 8
    for (int c = 0; c < NCH; ++c) {
        Ml = fmaxf(Ml, lm[b * NCH + c]);
        Mg = fmaxf(Mg, gm[b * NCH + c]);
    }
    float Sl = 0.f, Pl = 0.f, Sg = 0.f, Pg = 0.f;
    #pragma unroll 4
    for (int c = 0; c < NCH; ++c) {
        float wl = __expf(lm[b * NCH + c] - Ml);
        float wg = __expf(gm[b * NCH + c] - Mg);
        Sl += lS[b * NCH + c] * wl;
        Sg += gS[b * NCH + c] * wg;
        Pl += lP[((size_t)b * NCH + c) * DD + d] * wl;
        Pg += gP[((size_t)b * NCH + c) * DD + d] * wg;
    }
    float br = beta_raw[slot_idx[0]];
    float beta = 1.f / (1.f + __expf(-br));
    out_c[b * DD + d] = beta * Pl / Sl + (1.f - beta) * Pg / Sg;
}

extern "C" void kernel_launch(void* const* d_in, const int* in_sizes, int n_in,
                              void* d_out, int out_size, void* d_ws, size_t ws_size,
                              hipStream_t stream) {
    const float* x        = (const float*)d_in[0];
    const int*   x_len    = (const int*)d_in[1];
    const int*   slot_idx = (const int*)d_in[2];
    const float* w_score  = (const float*)d_in[3];
    // d_in[4] = b_score (softmax shift-invariant, unused)
    const float* Wq       = (const float*)d_in[5];
    // d_in[6] = bq (only affects shift-invariant t, unused)
    const float* Wk       = (const float*)d_in[7];
    const float* bk       = (const float*)d_in[8];
    const float* beta_raw = (const float*)d_in[9];

    float* out   = (float*)d_out;
    float* out_x = out;                           // [B,S,D]
    float* out_c = out + (size_t)BB * SS * DD;    // [B,D]

    float* ws = (float*)d_ws;
    float* xsum_part = ws;                        // 32*32*512 = 524288
    float* lP        = ws + 524288;               // 524288
    float* gP        = ws + 1048576;              // 524288
    float* v         = ws + 1572864;              // 16384
    float* lm        = ws + 1589248;              // 1024
    float* lS        = ws + 1590272;              // 1024
    float* gm        = ws + 1591296;              // 1024
    float* gS        = ws + 1592320;              // 1024

    k_pass1<<<dim3(BB, NCH), 256, 0, stream>>>(x, w_score, x_len, out_x, xsum_part, lP, lm, lS);
    k_v2<<<dim3(2, BB), 256, 0, stream>>>(xsum_part, Wk, Wq, bk, v);
    k_pass2<<<dim3(BB, NCH), 256, 0, stream>>>(x, v, x_len, gP, gm, gS);
    k_combine<<<BB, 512, 0, stream>>>(lP, lm, lS, gP, gm, gS, slot_idx, beta_raw, out_c);
}

// Round 8
// 77.024 us; speedup vs baseline: 2.7574x; 1.0857x over previous
//
#include <hip/hip_runtime.h>
#include <float.h>
#include <math.h>

#define BB 32
#define SS 1024
#define DD 512
#define NCH 32          // chunks per batch (32 rows each)
#define CROWS 32
#define RW 8            // rows per wave

typedef float f32x4 __attribute__((ext_vector_type(4)));

__device__ __forceinline__ float wave_reduce_add(float v) {
    #pragma unroll
    for (int m = 32; m >= 1; m >>= 1) v += __shfl_xor(v, m, 64);
    return v;
}

// ---------------- K1: copy + xsum partials + LOCAL online-softmax chunk partials ----
// grid (BB, NCH), 256 threads = 4 waves x 8 rows.  (unchanged from R5)
__global__ __launch_bounds__(256) void k_pass1(
    const float* __restrict__ x, const float* __restrict__ w_score,
    const int* __restrict__ x_len, float* __restrict__ out_x,
    float* __restrict__ xsum_part, float* __restrict__ lP,
    float* __restrict__ lm, float* __restrict__ lS)
{
    __shared__ float red_xsum[4][DD];
    __shared__ float red_ctx[4][DD];
    __shared__ float m_s[4], S_s[4];
    int b = blockIdx.x, sc = blockIdx.y;
    int wave = threadIdx.x >> 6, lane = threadIdx.x & 63, tid = threadIdx.x;
    int len = x_len[b];
    int s0 = sc * CROWS + wave * RW;
    size_t base = ((size_t)b * SS + s0) * DD;

    const f32x4* wr = (const f32x4*)w_score;
    f32x4 w0 = wr[lane], w1 = wr[lane + 64];

    f32x4 a[RW][2];
    #pragma unroll
    for (int r = 0; r < RW; ++r) {
        const f32x4* xr = (const f32x4*)(x + base + (size_t)r * DD);
        a[r][0] = xr[lane];
        a[r][1] = xr[lane + 64];
    }
    #pragma unroll
    for (int r = 0; r < RW; ++r) {
        f32x4* orow = (f32x4*)(out_x + base + (size_t)r * DD);
        __builtin_nontemporal_store(a[r][0], &orow[lane]);
        __builtin_nontemporal_store(a[r][1], &orow[lane + 64]);
    }
    float p[RW];
    f32x4 acc0 = {0,0,0,0}, acc1 = {0,0,0,0};
    #pragma unroll
    for (int r = 0; r < RW; ++r) {
        f32x4 t0 = a[r][0] * w0 + a[r][1] * w1;
        p[r] = t0.x + t0.y + t0.z + t0.w;
        acc0 += a[r][0];
        acc1 += a[r][1];
    }
    #pragma unroll
    for (int r = 0; r < RW; ++r) p[r] = wave_reduce_add(p[r]);
    float mw = -FLT_MAX;
    #pragma unroll
    for (int r = 0; r < RW; ++r) if (s0 + r < len) mw = fmaxf(mw, p[r]);
    float Sw = 0.f;
    f32x4 c0 = {0,0,0,0}, c1 = {0,0,0,0};
    #pragma unroll
    for (int r = 0; r < RW; ++r) {
        float wgt = (s0 + r < len) ? __expf(p[r] - mw) : 0.f;
        Sw += wgt;
        c0 += wgt * a[r][0];
        c1 += wgt * a[r][1];
    }
    f32x4* rx = (f32x4*)red_xsum[wave];
    f32x4* rc = (f32x4*)red_ctx[wave];
    rx[lane] = acc0; rx[lane + 64] = acc1;
    rc[lane] = c0;   rc[lane + 64] = c1;
    if (lane == 0) { m_s[wave] = mw; S_s[wave] = Sw; }
    __syncthreads();
    float mc = fmaxf(fmaxf(m_s[0], m_s[1]), fmaxf(m_s[2], m_s[3]));
    float e0 = __expf(m_s[0] - mc), e1 = __expf(m_s[1] - mc);
    float e2 = __expf(m_s[2] - mc), e3 = __expf(m_s[3] - mc);
    #pragma unroll
    for (int i = 0; i < 2; ++i) {
        int d = tid + i * 256;
        size_t off = ((size_t)b * NCH + sc) * DD + d;
        xsum_part[off] = red_xsum[0][d] + red_xsum[1][d] + red_xsum[2][d] + red_xsum[3][d];
        lP[off] = red_ctx[0][d]*e0 + red_ctx[1][d]*e1 + red_ctx[2][d]*e2 + red_ctx[3][d]*e3;
    }
    if (tid == 0) {
        lm[b * NCH + sc] = mc;
        lS[b * NCH + sc] = S_s[0]*e0 + S_s[1]*e1 + S_s[2]*e2 + S_s[3]*e3;
    }
}

// ---------------- K2: xsum_part -> xsum (tiny) ----------------
__global__ __launch_bounds__(512) void k_xsum(
    const float* __restrict__ xsum_part, float* __restrict__ xsum)
{
    int b = blockIdx.x, d = threadIdx.x;
    float s = 0.f;
    #pragma unroll 8
    for (int sc = 0; sc < NCH; ++sc)
        s += xsum_part[((size_t)b * NCH + sc) * DD + d];
    xsum[b * DD + d] = s;
}

// ---------------- K3: fused ks-slice + v partials ----------------
// grid (8 ec, 2 db, 4 bg), 256 threads.
// Phase A: ks[b][e] for e in ec-slice (redundant across db).
// Phase B: v_part[ec][b][d] = sum_{e in slice} ks[b][e] * Wq[d][e], d in db-half.
__global__ __launch_bounds__(256) void k_kv(
    const float* __restrict__ xsum, const float* __restrict__ Wk,
    const float* __restrict__ Wq, const float* __restrict__ bk,
    float* __restrict__ v_part)
{
    __shared__ float tile[256][65];   // phase B Wq tile (aliases over phase A xsl)
    __shared__ float ksl[8][64];
    float* xsl = &tile[0][0];         // [8][512] = 16 KB, dead before tile staged
    int ec = blockIdx.x, db = blockIdx.y, bg = blockIdx.z;
    int tid = threadIdx.x;

    // stage xsum for 8 batches: 4096 floats
    #pragma unroll
    for (int i = 0; i < 4; ++i) {
        int idx = tid + i * 256;          // f32x4 index, 1024 total
        int bi = idx >> 7, dl = (idx & 127) * 4;
        f32x4 vv = *(const f32x4*)(xsum + (size_t)(bg * 8 + bi) * DD + dl);
        float* dst = xsl + bi * DD + dl;
        dst[0] = vv.x; dst[1] = vv.y; dst[2] = vv.z; dst[3] = vv.w;
    }
    __syncthreads();

    // phase A: ks slice. thread: el = tid&63, bp = tid>>6 (batches bp, bp+4)
    int el = tid & 63, bp = tid >> 6;
    int e = ec * 64 + el;
    float kb = (float)SS * bk[e];
    float k0 = kb, k1 = kb;
    const float* xs0 = xsl + bp * DD;
    const float* xs1 = xsl + (bp + 4) * DD;
    #pragma unroll 8
    for (int d = 0; d < DD; ++d) {
        float w = Wk[(size_t)d * DD + e];
        k0 += xs0[d] * w;
        k1 += xs1[d] * w;
    }
    __syncthreads();              // xsl reads done before tile overwrite
    ksl[bp][el] = k0;
    ksl[bp + 4][el] = k1;

    // phase B: stage Wq [256 d rows of db-half][64 e of ec-slice]
    int d0 = db * 256;
    #pragma unroll
    for (int it = 0; it < 16; ++it) {
        int idx = tid + it * 256;
        int rowd = idx >> 4, col4 = idx & 15;
        f32x4 wv = *(const f32x4*)(Wq + (size_t)(d0 + rowd) * DD + ec * 64 + col4 * 4);
        float* dst = &tile[rowd][col4 * 4];
        dst[0] = wv.x; dst[1] = wv.y; dst[2] = wv.z; dst[3] = wv.w;
    }
    __syncthreads();
    float acc[8] = {0,0,0,0,0,0,0,0};
    #pragma unroll 8
    for (int e2 = 0; e2 < 64; ++e2) {
        float wq = tile[tid][e2];
        #pragma unroll
        for (int bi = 0; bi < 8; ++bi) acc[bi] += ksl[bi][e2] * wq;
    }
    #pragma unroll
    for (int bi = 0; bi < 8; ++bi) {
        int b = bg * 8 + bi;
        v_part[((size_t)ec * BB + b) * DD + d0 + tid] = acc[bi];
    }
}

// ---------------- K4: g-scores + GLOBAL online-softmax chunk partials ----------------
// (R5 version: reduces v_part in-kernel)
__global__ __launch_bounds__(256) void k_pass2(
    const float* __restrict__ x, const float* __restrict__ v_part,
    const int* __restrict__ x_len,
    float* __restrict__ gP, float* __restrict__ gm, float* __restrict__ gS)
{
    __shared__ float v_lds[DD];
    __shared__ float red_ctx[4][DD];
    __shared__ float m_s[4], S_s[4];
    int b = blockIdx.x, sc = blockIdx.y;
    int wave = threadIdx.x >> 6, lane = threadIdx.x & 63, tid = threadIdx.x;
    int len = x_len[b];
    int s0 = sc * CROWS + wave * RW;
    size_t base = ((size_t)b * SS + s0) * DD;

    #pragma unroll
    for (int i = 0; i < 2; ++i) {
        int d = tid + i * 256;
        float vv = 0.f;
        #pragma unroll
        for (int ec = 0; ec < 8; ++ec) vv += v_part[((size_t)ec * BB + b) * DD + d];
        v_lds[d] = vv;
    }
    __syncthreads();
    const f32x4* vr = (const f32x4*)v_lds;
    f32x4 v0 = vr[lane], v1 = vr[lane + 64];

    f32x4 a[RW][2];
    #pragma unroll
    for (int r = 0; r < RW; ++r) {
        const f32x4* xr = (const f32x4*)(x + base + (size_t)r * DD);
        a[r][0] = xr[lane];
        a[r][1] = xr[lane + 64];
    }
    float p[RW];
    #pragma unroll
    for (int r = 0; r < RW; ++r) {
        f32x4 t0 = a[r][0] * v0 + a[r][1] * v1;
        p[r] = t0.x + t0.y + t0.z + t0.w;
    }
    #pragma unroll
    for (int r = 0; r < RW; ++r)
        p[r] = wave_reduce_add(p[r]) * 0.04419417382415922f;
    float mw = -FLT_MAX;
    #pragma unroll
    for (int r = 0; r < RW; ++r) if (s0 + r < len) mw = fmaxf(mw, p[r]);
    float Sw = 0.f;
    f32x4 c0 = {0,0,0,0}, c1 = {0,0,0,0};
    #pragma unroll
    for (int r = 0; r < RW; ++r) {
        float wgt = (s0 + r < len) ? __expf(p[r] - mw) : 0.f;
        Sw += wgt;
        c0 += wgt * a[r][0];
        c1 += wgt * a[r][1];
    }
    f32x4* rc = (f32x4*)red_ctx[wave];
    rc[lane] = c0; rc[lane + 64] = c1;
    if (lane == 0) { m_s[wave] = mw; S_s[wave] = Sw; }
    __syncthreads();
    float mc = fmaxf(fmaxf(m_s[0], m_s[1]), fmaxf(m_s[2], m_s[3]));
    float e0 = __expf(m_s[0] - mc), e1 = __expf(m_s[1] - mc);
    float e2 = __expf(m_s[2] - mc), e3 = __expf(m_s[3] - mc);
    #pragma unroll
    for (int i = 0; i < 2; ++i) {
        int d = tid + i * 256;
        size_t off = ((size_t)b * NCH + sc) * DD + d;
        gP[off] = red_ctx[0][d]*e0 + red_ctx[1][d]*e1 + red_ctx[2][d]*e2 + red_ctx[3][d]*e3;
    }
    if (tid == 0) {
        gm[b * NCH + sc] = mc;
        gS[b * NCH + sc] = S_s[0]*e0 + S_s[1]*e1 + S_s[2]*e2 + S_s[3]*e3;
    }
}

// ---------------- K5: merge chunk partials, beta-combine ----------------
__global__ __launch_bounds__(512) void k_combine(
    const float* __restrict__ lP, const float* __restrict__ lm, const float* __restrict__ lS,
    const float* __restrict__ gP, const float* __restrict__ gm, const float* __restrict__ gS,
    const int* __restrict__ slot_idx, const float* __restrict__ beta_raw,
    float* __restrict__ out_c)
{
    int b = blockIdx.x, d = threadIdx.x;
    float Ml = -FLT_MAX, Mg = -FLT_MAX;
    #pragma unroll 8
    for (int c = 0; c < NCH; ++c) {
        Ml = fmaxf(Ml, lm[b * NCH + c]);
        Mg = fmaxf(Mg, gm[b * NCH + c]);
    }
    float Sl = 0.f, Pl = 0.f, Sg = 0.f, Pg = 0.f;
    #pragma unroll 4
    for (int c = 0; c < NCH; ++c) {
        float wl = __expf(lm[b * NCH + c] - Ml);
        float wg = __expf(gm[b * NCH + c] - Mg);
        Sl += lS[b * NCH + c] * wl;
        Sg += gS[b * NCH + c] * wg;
        Pl += lP[((size_t)b * NCH + c) * DD + d] * wl;
        Pg += gP[((size_t)b * NCH + c) * DD + d] * wg;
    }
    float br = beta_raw[slot_idx[0]];
    float beta = 1.f / (1.f + __expf(-br));
    out_c[b * DD + d] = beta * Pl / Sl + (1.f - beta) * Pg / Sg;
}

extern "C" void kernel_launch(void* const* d_in, const int* in_sizes, int n_in,
                              void* d_out, int out_size, void* d_ws, size_t ws_size,
                              hipStream_t stream) {
    const float* x        = (const float*)d_in[0];
    const int*   x_len    = (const int*)d_in[1];
    const int*   slot_idx = (const int*)d_in[2];
    const float* w_score  = (const float*)d_in[3];
    // d_in[4] = b_score (softmax shift-invariant, unused)
    const float* Wq       = (const float*)d_in[5];
    // d_in[6] = bq (only affects shift-invariant t, unused)
    const float* Wk       = (const float*)d_in[7];
    const float* bk       = (const float*)d_in[8];
    const float* beta_raw = (const float*)d_in[9];

    float* out   = (float*)d_out;
    float* out_x = out;                           // [B,S,D]
    float* out_c = out + (size_t)BB * SS * DD;    // [B,D]

    float* ws = (float*)d_ws;
    float* xsum_part = ws;                        // 32*32*512 = 524288
    float* lP        = ws + 524288;               // 524288
    float* gP        = ws + 1048576;              // 524288
    float* v_part    = ws + 1572864;              // 8*32*512 = 131072
    float* xsum      = ws + 1703936;              // 16384
    float* lm        = ws + 1720320;              // 1024
    float* lS        = ws + 1721344;              // 1024
    float* gm        = ws + 1722368;              // 1024
    float* gS        = ws + 1723392;              // 1024

    k_pass1<<<dim3(BB, NCH), 256, 0, stream>>>(x, w_score, x_len, out_x, xsum_part, lP, lm, lS);
    k_xsum<<<BB, 512, 0, stream>>>(xsum_part, xsum);
    k_kv<<<dim3(8, 2, 4), 256, 0, stream>>>(xsum, Wk, Wq, bk, v_part);
    k_pass2<<<dim3(BB, NCH), 256, 0, stream>>>(x, v_part, x_len, gP, gm, gS);
    k_combine<<<BB, 512, 0, stream>>>(lP, lm, lS, gP, gm, gS, slot_idx, beta_raw, out_c);
}

// Round 9
// 57.425 us; speedup vs baseline: 3.6985x; 1.3413x over previous
//
#include <hip/hip_runtime.h>
#include <float.h>
#include <math.h>

#define BB 32
#define SS 1024
#define DD 512
#define NCH 32          // softmax chunks per batch (32 rows each)
#define CROWS 32
#define RW 8            // rows per wave
#define NXCH 16         // xsum chunks per batch (64 rows each)

typedef float f32x4 __attribute__((ext_vector_type(4)));
typedef float f32x2 __attribute__((ext_vector_type(2)));

__device__ __forceinline__ float wave_reduce_add(float v) {
    #pragma unroll
    for (int m = 32; m >= 1; m >>= 1) v += __shfl_xor(v, m, 64);
    return v;
}

// ---------------- K1: xsum partials straight from x ----------------
// grid (NXCH, BB), 256 threads; each block streams 64 contiguous rows.
__global__ __launch_bounds__(256) void k_xsumx(
    const float* __restrict__ x, float* __restrict__ xsum_part)
{
    int sc = blockIdx.x, b = blockIdx.y, tid = threadIdx.x;
    const float* xb = x + ((size_t)b * SS + sc * 64) * DD + tid * 2;
    f32x2 acc = {0.f, 0.f};
    #pragma unroll 8
    for (int r = 0; r < 64; ++r)
        acc += *(const f32x2*)(xb + (size_t)r * DD);
    *(f32x2*)(xsum_part + ((size_t)b * NXCH + sc) * DD + tid * 2) = acc;
}

// ---------------- K2: ks partials: ks_part[dc][b][e] ----------------
// grid (8 dc, 2 eb, 4 bg), 256 threads. Inner loop 64-deep, coalesced Wk rows.
__global__ __launch_bounds__(256) void k_ks(
    const float* __restrict__ xsum_part, const float* __restrict__ Wk,
    float* __restrict__ ks_part)
{
    __shared__ float xs[8][64];
    int dc = blockIdx.x, eb = blockIdx.y, bg = blockIdx.z;
    int tid = threadIdx.x;
    int e = eb * 256 + tid;
    #pragma unroll
    for (int k = 0; k < 2; ++k) {
        int i = tid + k * 256;
        int bi = i >> 6, dl = i & 63;
        int b = bg * 8 + bi, d = dc * 64 + dl;
        float v = 0.f;
        #pragma unroll
        for (int scc = 0; scc < NXCH; ++scc)
            v += xsum_part[((size_t)b * NXCH + scc) * DD + d];
        xs[bi][dl] = v;
    }
    __syncthreads();
    float acc[8] = {0,0,0,0,0,0,0,0};
    #pragma unroll 8
    for (int dl = 0; dl < 64; ++dl) {
        float w = Wk[(size_t)(dc * 64 + dl) * DD + e];
        #pragma unroll
        for (int bi = 0; bi < 8; ++bi) acc[bi] += xs[bi][dl] * w;
    }
    #pragma unroll
    for (int bi = 0; bi < 8; ++bi) {
        int b = bg * 8 + bi;
        ks_part[((size_t)dc * BB + b) * DD + e] = acc[bi];
    }
}

// ---------------- K3: v partials: v_part[ec][b][d] ----------------
// grid (8 ec, 2 db, 4 bg), 256 threads. (R5's proven k_v)
__global__ __launch_bounds__(256) void k_v(
    const float* __restrict__ ks_part, const float* __restrict__ Wq,
    const float* __restrict__ bk, float* __restrict__ v_part)
{
    __shared__ float wq_lds[256 * 65];
    __shared__ float ks_lds[8][64];
    int ec = blockIdx.x, db = blockIdx.y, bg = blockIdx.z;
    int tid = threadIdx.x;
    #pragma unroll
    for (int k = 0; k < 2; ++k) {
        int i = tid + k * 256;
        int bi = i >> 6, el = i & 63;
        int b = bg * 8 + bi, e = ec * 64 + el;
        float val = (float)SS * bk[e];
        #pragma unroll
        for (int dcc = 0; dcc < 8; ++dcc)
            val += ks_part[((size_t)dcc * BB + b) * DD + e];
        ks_lds[bi][el] = val;
    }
    #pragma unroll
    for (int it = 0; it < 16; ++it) {
        int idx = tid + it * 256;
        int rowd = idx >> 4, col4 = idx & 15;
        f32x4 wv = *(const f32x4*)(Wq + (size_t)(db * 256 + rowd) * DD + ec * 64 + col4 * 4);
        float* dst = &wq_lds[rowd * 65 + col4 * 4];
        dst[0] = wv.x; dst[1] = wv.y; dst[2] = wv.z; dst[3] = wv.w;
    }
    __syncthreads();
    float acc[8] = {0,0,0,0,0,0,0,0};
    #pragma unroll 8
    for (int el = 0; el < 64; ++el) {
        float wq = wq_lds[tid * 65 + el];
        #pragma unroll
        for (int bi = 0; bi < 8; ++bi) acc[bi] += ks_lds[bi][el] * wq;
    }
    int d = db * 256 + tid;
    #pragma unroll
    for (int bi = 0; bi < 8; ++bi) {
        int b = bg * 8 + bi;
        v_part[((size_t)ec * BB + b) * DD + d] = acc[bi];
    }
}

// ---------------- K4: SINGLE pass over x: copy + BOTH score branches ----------------
// grid (BB, NCH), 256 threads = 4 waves x 8 rows.
__global__ __launch_bounds__(256) void k_pass1full(
    const float* __restrict__ x, const float* __restrict__ w_score,
    const float* __restrict__ v_part, const int* __restrict__ x_len,
    float* __restrict__ out_x,
    float* __restrict__ lP, float* __restrict__ lm, float* __restrict__ lS,
    float* __restrict__ gP, float* __restrict__ gm, float* __restrict__ gS)
{
    __shared__ float v_lds[DD];
    __shared__ float red_l[4][DD];
    __shared__ float red_g[4][DD];
    __shared__ float msl[4], Ssl[4], msg[4], Ssg[4];
    int b = blockIdx.x, sc = blockIdx.y;
    int wave = threadIdx.x >> 6, lane = threadIdx.x & 63, tid = threadIdx.x;
    int len = x_len[b];
    int s0 = sc * CROWS + wave * RW;
    size_t base = ((size_t)b * SS + s0) * DD;

    // reduce v_part (L2-resident) into LDS
    #pragma unroll
    for (int i = 0; i < 2; ++i) {
        int d = tid + i * 256;
        float vv = 0.f;
        #pragma unroll
        for (int ec = 0; ec < 8; ++ec) vv += v_part[((size_t)ec * BB + b) * DD + d];
        v_lds[d] = vv;
    }
    __syncthreads();
    const f32x4* vr = (const f32x4*)v_lds;
    f32x4 v0 = vr[lane], v1 = vr[lane + 64];
    const f32x4* wr = (const f32x4*)w_score;
    f32x4 w0 = wr[lane], w1 = wr[lane + 64];

    f32x4 a[RW][2];
    #pragma unroll
    for (int r = 0; r < RW; ++r) {
        const f32x4* xr = (const f32x4*)(x + base + (size_t)r * DD);
        a[r][0] = xr[lane];
        a[r][1] = xr[lane + 64];
    }
    #pragma unroll
    for (int r = 0; r < RW; ++r) {
        f32x4* orow = (f32x4*)(out_x + base + (size_t)r * DD);
        __builtin_nontemporal_store(a[r][0], &orow[lane]);
        __builtin_nontemporal_store(a[r][1], &orow[lane + 64]);
    }
    float pl[RW], pg[RW];
    #pragma unroll
    for (int r = 0; r < RW; ++r) {
        f32x4 t0 = a[r][0] * w0 + a[r][1] * w1;
        pl[r] = t0.x + t0.y + t0.z + t0.w;
        f32x4 u0 = a[r][0] * v0 + a[r][1] * v1;
        pg[r] = u0.x + u0.y + u0.z + u0.w;
    }
    #pragma unroll
    for (int r = 0; r < RW; ++r) {
        pl[r] = wave_reduce_add(pl[r]);
        pg[r] = wave_reduce_add(pg[r]) * 0.04419417382415922f;
    }
    float mwl = -FLT_MAX, mwg = -FLT_MAX;
    #pragma unroll
    for (int r = 0; r < RW; ++r) {
        if (s0 + r < len) {
            mwl = fmaxf(mwl, pl[r]);
            mwg = fmaxf(mwg, pg[r]);
        }
    }
    float Swl = 0.f, Swg = 0.f;
    f32x4 cl0 = {0,0,0,0}, cl1 = {0,0,0,0}, cg0 = {0,0,0,0}, cg1 = {0,0,0,0};
    #pragma unroll
    for (int r = 0; r < RW; ++r) {
        bool valid = (s0 + r) < len;
        float wl = valid ? __expf(pl[r] - mwl) : 0.f;
        float wg = valid ? __expf(pg[r] - mwg) : 0.f;
        Swl += wl; Swg += wg;
        cl0 += wl * a[r][0]; cl1 += wl * a[r][1];
        cg0 += wg * a[r][0]; cg1 += wg * a[r][1];
    }
    f32x4* rl = (f32x4*)red_l[wave];
    f32x4* rg = (f32x4*)red_g[wave];
    rl[lane] = cl0; rl[lane + 64] = cl1;
    rg[lane] = cg0; rg[lane + 64] = cg1;
    if (lane == 0) { msl[wave] = mwl; Ssl[wave] = Swl; msg[wave] = mwg; Ssg[wave] = Swg; }
    __syncthreads();
    float mcl = fmaxf(fmaxf(msl[0], msl[1]), fmaxf(msl[2], msl[3]));
    float mcg = fmaxf(fmaxf(msg[0], msg[1]), fmaxf(msg[2], msg[3]));
    float el0 = __expf(msl[0] - mcl), el1 = __expf(msl[1] - mcl);
    float el2 = __expf(msl[2] - mcl), el3 = __expf(msl[3] - mcl);
    float eg0 = __expf(msg[0] - mcg), eg1 = __expf(msg[1] - mcg);
    float eg2 = __expf(msg[2] - mcg), eg3 = __expf(msg[3] - mcg);
    #pragma unroll
    for (int i = 0; i < 2; ++i) {
        int d = tid + i * 256;
        size_t off = ((size_t)b * NCH + sc) * DD + d;
        lP[off] = red_l[0][d]*el0 + red_l[1][d]*el1 + red_l[2][d]*el2 + red_l[3][d]*el3;
        gP[off] = red_g[0][d]*eg0 + red_g[1][d]*eg1 + red_g[2][d]*eg2 + red_g[3][d]*eg3;
    }
    if (tid == 0) {
        lm[b * NCH + sc] = mcl;
        lS[b * NCH + sc] = Ssl[0]*el0 + Ssl[1]*el1 + Ssl[2]*el2 + Ssl[3]*el3;
        gm[b * NCH + sc] = mcg;
        gS[b * NCH + sc] = Ssg[0]*eg0 + Ssg[1]*eg1 + Ssg[2]*eg2 + Ssg[3]*eg3;
    }
}

// ---------------- K5: merge chunk partials, beta-combine ----------------
__global__ __launch_bounds__(512) void k_combine(
    const float* __restrict__ lP, const float* __restrict__ lm, const float* __restrict__ lS,
    const float* __restrict__ gP, const float* __restrict__ gm, const float* __restrict__ gS,
    const int* __restrict__ slot_idx, const float* __restrict__ beta_raw,
    float* __restrict__ out_c)
{
    int b = blockIdx.x, d = threadIdx.x;
    float Ml = -FLT_MAX, Mg = -FLT_MAX;
    #pragma unroll 8
    for (int c = 0; c < NCH; ++c) {
        Ml = fmaxf(Ml, lm[b * NCH + c]);
        Mg = fmaxf(Mg, gm[b * NCH + c]);
    }
    float Sl = 0.f, Pl = 0.f, Sg = 0.f, Pg = 0.f;
    #pragma unroll 4
    for (int c = 0; c < NCH; ++c) {
        float wl = __expf(lm[b * NCH + c] - Ml);
        float wg = __expf(gm[b * NCH + c] - Mg);
        Sl += lS[b * NCH + c] * wl;
        Sg += gS[b * NCH + c] * wg;
        Pl += lP[((size_t)b * NCH + c) * DD + d] * wl;
        Pg += gP[((size_t)b * NCH + c) * DD + d] * wg;
    }
    float br = beta_raw[slot_idx[0]];
    float beta = 1.f / (1.f + __expf(-br));
    out_c[b * DD + d] = beta * Pl / Sl + (1.f - beta) * Pg / Sg;
}

extern "C" void kernel_launch(void* const* d_in, const int* in_sizes, int n_in,
                              void* d_out, int out_size, void* d_ws, size_t ws_size,
                              hipStream_t stream) {
    const float* x        = (const float*)d_in[0];
    const int*   x_len    = (const int*)d_in[1];
    const int*   slot_idx = (const int*)d_in[2];
    const float* w_score  = (const float*)d_in[3];
    // d_in[4] = b_score (softmax shift-invariant, unused)
    const float* Wq       = (const float*)d_in[5];
    // d_in[6] = bq (only affects shift-invariant t, unused)
    const float* Wk       = (const float*)d_in[7];
    const float* bk       = (const float*)d_in[8];
    const float* beta_raw = (const float*)d_in[9];

    float* out   = (float*)d_out;
    float* out_x = out;                           // [B,S,D]
    float* out_c = out + (size_t)BB * SS * DD;    // [B,D]

    float* ws = (float*)d_ws;
    float* xsum_part = ws;                        // 32*16*512 = 262144
    float* ks_part   = ws + 262144;               // 8*32*512  = 131072
    float* v_part    = ws + 393216;               // 8*32*512  = 131072
    float* lP        = ws + 524288;               // 524288
    float* gP        = ws + 1048576;              // 524288
    float* lm        = ws + 1572864;              // 1024
    float* lS        = ws + 1573888;              // 1024
    float* gm        = ws + 1574912;               // 1024
    float* gS        = ws + 1575936;              // 1024

    k_xsumx<<<dim3(NXCH, BB), 256, 0, stream>>>(x, xsum_part);
    k_ks<<<dim3(8, 2, 4), 256, 0, stream>>>(xsum_part, Wk, ks_part);
    k_v<<<dim3(8, 2, 4), 256, 0, stream>>>(ks_part, Wq, bk, v_part);
    k_pass1full<<<dim3(BB, NCH), 256, 0, stream>>>(x, w_score, v_part, x_len, out_x,
                                                   lP, lm, lS, gP, gm, gS);
    k_combine<<<BB, 512, 0, stream>>>(lP, lm, lS, gP, gm, gS, slot_idx, beta_raw, out_c);
}